// Round 8
// baseline (185.876 us; speedup 1.0000x reference)
//
#include <hip/hip_runtime.h>
#include <hip/hip_bf16.h>
#include <math.h>

// ---------------------------------------------------------------------------
// CgpHmmCell forward: 512 seqs x 2048 steps x 25-state HMM (23 live states;
// states 23/24 emit only 'X' which never occurs in tokens in [0,4)).
//
// SINGLE-KERNEL design: one block = one sequence, 1024 threads = 32 groups
// x 32 lanes; group = chunk of 64 steps, lane = basis row. Tokens staged to
// LDS; per-block private setup; chunk transfer matrices in LDS (bf16 +
// fp32 log-scale); wave 0 folds them.
//
// Round-7 lesson (counter-modeled): the scan was LDS-PIPE bound — 6
// broadcast ds_read_b128 per step at ~10 cyc serialized across all resident
// waves explains rounds 5/6/7 wall times. Fix: emission rows packed bf16
// (48 B) -> 3 ds_read_b128 per step. Unpack: even states exact (u<<16),
// odd states use the raw uint UNMASKED (garbage low mantissa <= 2^-8 rel,
// same as bf16 rounding; structural zeros become ~1e-39 and still die).
//
// Round-4 lesson: never clamp VGPRs below the live set (scratch spill).
// Round-5 lesson: stay under the 64-VGPR occupancy cliff (weights in SGPRs).
// Round-6 lesson: never leave a dependent GLOBAL load exposed in the body
// (tokens now come from LDS, so the global prefetch regs are gone).
// ---------------------------------------------------------------------------

#define NSTATES 25
#define NLIVE   23
#define NFLAT   216
#define NPACK   100
#define TLEN    2048
#define NSEQ    512
#define CHUNKS  32
#define CLEN    64

// ---------------------------------------------------------------------------
// Compile-time emission map: WMAP[state*216+flat] = k-index into wE,
// -1 = non-trainable (logit 1.0), -2 = absent. (Validated: absmax 0.0.)
// ---------------------------------------------------------------------------
struct WMap { short m[NSTATES * NFLAT]; };

constexpr WMap make_wmap() {
  WMap w{};
  for (int i = 0; i < NSTATES * NFLAT; i++) w.m[i] = -2;
  const unsigned char ST[29] = {0,1,2,3,4,5,6,7,8,9,10,11,11,12,12,12,13,
                                14,15,16,17,18,19,20,21,22,23,23,24};
  const unsigned char M1[29] = {0x1F,0x1F,0x1F,0x11,0x18,0x14,0x1F,0x1F,0x1F,
                                0x1F,0x0F,0x0F,0x0F,0x08,0x08,0x08,0x0F,
                                0x1F,0x1F,0x1F,0x1F,0x1F,0x1F,0x1F,0x1F,0x1F,
                                0x0F,0x0F,0x20};
  const unsigned char M2[29] = {0x1F,0x1F,0x11,0x18,0x14,0x1F,0x1F,0x1F,0x1F,
                                0x1F,0x0F,0x08,0x08,0x01,0x01,0x04,0x0F,
                                0x1F,0x1F,0x1F,0x1F,0x1F,0x1F,0x1F,0x1F,0x1F,
                                0x0F,0x20,0x20};
  const unsigned char M3[29] = {0x0F,0x01,0x08,0x04,0x0F,0x0F,0x0F,0x0F,0x0F,
                                0x0F,0x08,0x01,0x04,0x01,0x04,0x01,0x0F,
                                0x0F,0x0F,0x0F,0x0F,0x0F,0x0F,0x0F,0x0F,0x0F,
                                0x20,0x20,0x20};
  const unsigned char TR[29] = {1,1,1,0,1,1,1,1,1,1,1,1,1,0,0,0,1,
                                1,1,1,1,1,1,1,1,1,1,1,0};
  int k = 0;
  for (int s = 0; s < 29; s++) {
    for (int c1 = 0; c1 < 6; c1++) {
      if (!((M1[s] >> c1) & 1)) continue;
      for (int c2 = 0; c2 < 6; c2++) {
        if (!((M2[s] >> c2) & 1)) continue;
        if (c1 != 4 && c2 == 4) continue;  // pad-4 only as prefix (ORDER=2)
        for (int c3 = 0; c3 < 6; c3++) {
          if (!((M3[s] >> c3) & 1)) continue;
          w.m[ST[s] * NFLAT + c1 * 36 + c2 * 6 + c3] =
              TR[s] ? (short)(k++) : (short)-1;
        }
      }
    }
  }
  return w;
}
__device__ __constant__ WMap WMAP = make_wmap();

__device__ __forceinline__ unsigned short f2bf(float x) {  // RNE
  unsigned int u = __float_as_uint(x);
  u += 0x7fffu + ((u >> 16) & 1u);
  return (unsigned short)(u >> 16);
}

// bf16 pair unpack: lo exact; hi UNMASKED (low-16 garbage <= 2^-8 rel noise,
// same order as the bf16 quantization itself — saves 12 v_and per step).
__device__ __forceinline__ float blo(unsigned u) {
  return __uint_as_float(u << 16);
}
__device__ __forceinline__ float bhi(unsigned u) {
  return __uint_as_float(u);
}

// ---------------------------------------------------------------------------
// One HMM step over the 23 live states. Emission row = 24 packed bf16
// (48 B, 3 ds_read_b128), group-uniform idx.
// ---------------------------------------------------------------------------
__device__ __forceinline__ void hmm_step(float (&a)[NLIVE], const float (&w)[21],
                                         const unsigned short* __restrict__ ep,
                                         int idx) {
  const uint4* er = (const uint4*)(ep + idx * 24);
  uint4 r0 = er[0];
  uint4 r1 = er[1];
  uint4 r2 = er[2];

  float n0  = a[0]*w[0];
  float n1  = a[0]*w[1];
  float n4  = a[3]*w[2]  + a[16]*w[13];
  float n7  = a[3]*w[4]  + a[6]*w[6]  + a[19]*w[15];
  float n10 = a[3]*w[5]  + a[6]*w[8]  + a[9]*w[10] + a[22]*w[17];
  float n13 = a[12]      + a[13]*w[11];
  float n14 = a[3]*w[3]  + a[16]*w[14];
  float n17 = a[6]*w[7]  + a[19]*w[16];
  float n20 = a[9]*w[9]  + a[22]*w[18];
  float o2 = a[1],  o3 = a[2],  o5 = a[4],  o6 = a[5];
  float o8 = a[7],  o9 = a[8],  o11 = a[10], o12 = a[11];
  float o15 = a[14], o16 = a[15], o18 = a[17], o19 = a[18];
  float o21 = a[20], o22 = a[21];

  a[0]  = n0  * blo(r0.x);  a[1]  = n1  * bhi(r0.x);
  a[2]  = o2  * blo(r0.y);  a[3]  = o3  * bhi(r0.y);
  a[4]  = n4  * blo(r0.z);  a[5]  = o5  * bhi(r0.z);
  a[6]  = o6  * blo(r0.w);  a[7]  = n7  * bhi(r0.w);
  a[8]  = o8  * blo(r1.x);  a[9]  = o9  * bhi(r1.x);
  a[10] = n10 * blo(r1.y);  a[11] = o11 * bhi(r1.y);
  a[12] = o12 * blo(r1.z);  a[13] = n13 * bhi(r1.z);
  a[14] = n14 * blo(r1.w);  a[15] = o15 * bhi(r1.w);
  a[16] = o16 * blo(r2.x);  a[17] = n17 * bhi(r2.x);
  a[18] = o18 * blo(r2.y);  a[19] = o19 * bhi(r2.y);
  a[20] = n20 * blo(r2.z);  a[21] = o21 * bhi(r2.z);
  a[22] = o22 * blo(r2.w);
}

__device__ __forceinline__ void renorm(float (&a)[NLIVE], float& L) {
  float s = (((a[0]+a[1])+(a[2]+a[3])) + ((a[4]+a[5])+(a[6]+a[7])))
          + (((a[8]+a[9])+(a[10]+a[11])) + ((a[12]+a[13])+(a[14]+a[15])))
          + (((a[16]+a[17])+(a[18]+a[19])) + ((a[20]+a[21])+a[22]));
  if (s > 0.0f) {
    L += __logf(s);
    float r = __fdividef(1.0f, s);
    #pragma unroll
    for (int j = 0; j < NLIVE; j++) a[j] *= r;
  } else {
    L = -3.0e38f;  // row died; stays dead
  }
}

// context update: consume token nt. idx = c12*4+nt; c12' = p2*5+nt; p2' = nt.
#define STEP(nt_) { int nt = (nt_); hmm_step(a, w, sEp, (c12 << 2) + nt); \
                    c12 = p2 * 5 + nt; p2 = nt; }

// ---------------------------------------------------------------------------
// The whole problem in one kernel: block = one sequence.
// ---------------------------------------------------------------------------
__global__ __launch_bounds__(1024)
void hmm_kernel(const float* __restrict__ wT, const float* __restrict__ wE,
                const float* __restrict__ wI, const int* __restrict__ tokens,
                float* __restrict__ out) {
  __shared__ __align__(16) int sTok[TLEN];                          //  8192 B
  __shared__ __align__(16) unsigned short sEp[NPACK * 24];          //  4800 B
  __shared__ __align__(16) unsigned short sT[CHUNKS * NLIVE * 24];  // 35328 B
  __shared__ float sL[CHUNKS * NLIVE];                              //  2944 B
  __shared__ float sAW[24];
  __shared__ float sI[32];

  const int tid  = threadIdx.x;
  const int seq  = blockIdx.x;
  const int* trow = tokens + (size_t)seq * TLEN;

  // ---- stage tokens (fully coalesced: 8 B per thread) ----
  *(int2*)&sTok[2 * tid] = *(const int2*)(trow + 2 * tid);

  const int chunk = tid >> 5;
  const int row   = tid & 31;

  // ---- per-block setup into LDS ----
  if (chunk < NSTATES) {
    const int st = chunk;
    float part = 0.0f;
    for (int c = row; c < NFLAT; c += 32) {
      short m = WMAP.m[st * NFLAT + c];
      if (m == -1) part += expf(1.0f);
      else if (m >= 0) part += expf(wE[m]);
    }
    #pragma unroll
    for (int m = 1; m < 32; m <<= 1) part += __shfl_xor(part, m, 32);
    float inv = 1.0f / part;
    for (int i = row; i < NPACK; i += 32) {
      int c12 = i >> 2, nt = i & 3;
      int p1 = c12 / 5, p2v = c12 - 5 * p1;
      int flat = p1 * 36 + p2v * 6 + nt;
      short m = WMAP.m[st * NFLAT + flat];
      float v = 0.0f;
      if (m == -1) v = expf(1.0f);
      else if (m >= 0) v = expf(wE[m]);
      sEp[i * 24 + st] = f2bf(v * inv);
    }
    if (row < 24 - NLIVE)  // zero the pad element (state 23 slot)
      ; // sEp[... + 23] written below by lane pattern; do explicitly:
    if (row == 0)
      for (int i = 0; i < NPACK; i++) sEp[i * 24 + 23] = 0;  // st==0 group only
  } else if (chunk == 25 && row == 0) {
    // softmax of multi-entry A rows -> 21 packed weights (validated)
    const float w0 = wT[0], w1 = wT[1], w2 = wT[2], w3 = wT[3], w4 = wT[4];
    const float w5 = wT[5], w6 = wT[6], w7 = wT[7], w8 = wT[8], w9 = wT[9];
    { float e0 = expf(1.0f - w0), e1 = expf(w0), is = 1.0f / (e0 + e1);
      sAW[0] = e0 * is; sAW[1] = e1 * is; }
    { float e4 = expf(w1), e14 = expf(w3);
      float e7 = expf(1.0f - w9 * w9), e10 = expf(1.0f - w9 * w9 * w9);
      float is = 1.0f / (e4 + e14 + e7 + e10);
      sAW[2] = e4 * is;  sAW[3] = e14 * is;
      sAW[4] = e7 * is;  sAW[5] = e10 * is; }
    { float e7 = expf(w2), e17 = expf(w4), e10 = expf(1.0f - w9 * w9);
      float is = 1.0f / (e7 + e17 + e10);
      sAW[6] = e7 * is; sAW[7] = e17 * is; sAW[8] = e10 * is; }
    { float e20 = expf(w5), e10 = expf(1.0f - w5), is = 1.0f / (e20 + e10);
      sAW[9] = e20 * is; sAW[10] = e10 * is; }
    sAW[11] = 0.5f; sAW[12] = 0.5f;   // row 13
    { float e4 = expf(w6), e14 = expf(1.0f - w6), is = 1.0f / (e4 + e14);
      sAW[13] = e4 * is; sAW[14] = e14 * is; }
    { float e7 = expf(w7), e17 = expf(1.0f - w7), is = 1.0f / (e7 + e17);
      sAW[15] = e7 * is; sAW[16] = e17 * is; }
    { float e10 = expf(w8), e20 = expf(1.0f - w8), is = 1.0f / (e10 + e20);
      sAW[17] = e10 * is; sAW[18] = e20 * is; }
    sAW[19] = 0.5f; sAW[20] = 0.5f;
  } else if (chunk == 25 && row == 1) {
    float e[9], s = 0.0f;
    for (int i = 0; i < 9; i++) { e[i] = expf(wI[i]); s += e[i]; }
    float inv = 1.0f / s;
    for (int i = 0; i < 9; i++) sI[i] = e[i] * inv;
    for (int i = 9; i < 32; i++) sI[i] = 0.0f;
  }
  __syncthreads();

  // A-weights: wave-uniform -> SGPRs (stay under the 64-VGPR cliff)
  float w[21];
  #pragma unroll
  for (int i = 0; i < 21; i++)
    w[i] = __uint_as_float(
        (unsigned)__builtin_amdgcn_readfirstlane(__float_as_uint(sAW[i])));

  // ---- scan: group = chunk of 64 steps, lane = basis row ----
  const int t0 = chunk * CLEN;

  float a[NLIVE];
  #pragma unroll
  for (int j = 0; j < NLIVE; j++) a[j] = 0.0f;
  if (row < NLIVE) a[row] = 1.0f;
  float L = 0.0f;

  int c12, p2;
  int b = 0;
  if (chunk == 0) {
    // body 0 = steps t = 1..7 (t = 0 is folded into the combine's init)
    int4 q0 = *(const int4*)&sTok[0];
    int4 q1 = *(const int4*)&sTok[4];
    c12 = 20 + q0.x; p2 = q0.x;   // context (4, tok0)
    STEP(q0.y); STEP(q0.z); STEP(q0.w);
    STEP(q1.x); STEP(q1.y); STEP(q1.z); STEP(q1.w);
    renorm(a, L);
    b = 1;
  } else {
    c12 = sTok[t0 - 2] * 5 + sTok[t0 - 1];
    p2 = sTok[t0 - 1];
  }

  for (; b < CLEN / 8; b++) {
    int4 q0 = *(const int4*)&sTok[t0 + b * 8];
    int4 q1 = *(const int4*)&sTok[t0 + b * 8 + 4];
    STEP(q0.x); STEP(q0.y); STEP(q0.z); STEP(q0.w);
    STEP(q1.x); STEP(q1.y); STEP(q1.z); STEP(q1.w);
    renorm(a, L);
  }

  // stash chunk matrix row in LDS (bf16 values, fp32 L)
  if (row < NLIVE) {
    const int base = (chunk * NLIVE + row) * 24;
    #pragma unroll
    for (int k = 0; k < 11; k++) {
      ushort2 p; p.x = f2bf(a[2 * k]); p.y = f2bf(a[2 * k + 1]);
      *(ushort2*)&sT[base + 2 * k] = p;
    }
    { ushort2 p; p.x = f2bf(a[22]); p.y = 0; *(ushort2*)&sT[base + 22] = p; }
    sL[chunk * NLIVE + row] = L;
  }
  __syncthreads();

  // ---- combine (wave 0 only): fold 32 chunk matrices, lane j = column j ----
  if (tid < 64) {
    const int lane = tid;
    const bool act = (lane < NLIVE);
    const int jc   = act ? lane : 0;

    const int tok0 = sTok[0];
    const int idx0 = 96 + tok0;   // packed (4,4,tok0)

    float e0j = __uint_as_float(((unsigned)sEp[idx0 * 24 + jc]) << 16);
    float v = act ? sI[lane] * e0j : 0.0f;
    float s = v;
    #pragma unroll
    for (int m = 1; m < 32; m <<= 1) s += __shfl_xor(s, m, 32);
    float ll = __logf(s);
    v = act ? v * __fdividef(1.0f, s) : 0.0f;

    for (int c = 0; c < CHUNKS; c++) {
      float Lj  = act ? sL[c * NLIVE + lane] : -3.0e38f;
      float key = (act && v > 0.0f) ? Lj : -3.0e38f;
      float mx = key;
      #pragma unroll
      for (int m = 1; m < 32; m <<= 1) mx = fmaxf(mx, __shfl_xor(mx, m, 32));
      float wgt = (act && v > 0.0f) ? v * __expf(Lj - mx) : 0.0f;

      float nv = 0.0f;
      #pragma unroll
      for (int r = 0; r < NLIVE; r++) {
        float wr = __shfl(wgt, r, 64);
        nv += wr * __uint_as_float(((unsigned)sT[(c * NLIVE + r) * 24 + jc]) << 16);
      }
      float nva = act ? nv : 0.0f;
      float s2 = nva;
      #pragma unroll
      for (int m = 1; m < 32; m <<= 1) s2 += __shfl_xor(s2, m, 32);
      ll += mx + __logf(s2);
      v = act ? nv * __fdividef(1.0f, s2) : 0.0f;
    }

    if (lane == 0) out[seq] = ll;
  }
}

// ---------------------------------------------------------------------------
extern "C" void kernel_launch(void* const* d_in, const int* in_sizes, int n_in,
                              void* d_out, int out_size, void* d_ws, size_t ws_size,
                              hipStream_t stream) {
  const float* wT = (const float*)d_in[0];   // transition_kernel (10)
  const float* wE = (const float*)d_in[1];   // emission_kernel (5400)
  const float* wI = (const float*)d_in[2];   // init_kernel (25)
  const int* tokens = (const int*)d_in[3];   // (512, 2048) int32
  float* out = (float*)d_out;                // (512,) float32
  (void)d_ws; (void)ws_size;                 // workspace unused

  hmm_kernel<<<NSEQ, 1024, 0, stream>>>(wT, wE, wI, tokens, out);
}

// Round 9
// 174.950 us; speedup vs baseline: 1.0625x; 1.0625x over previous
//
#include <hip/hip_runtime.h>
#include <hip/hip_bf16.h>
#include <math.h>

// ---------------------------------------------------------------------------
// CgpHmmCell forward: 512 seqs x 2048 steps x 25-state HMM (23 live states;
// states 23/24 emit only 'X' which never occurs in tokens in [0,4)).
//
// SINGLE-KERNEL: one block = one sequence, 1024 threads = 32 groups x 32
// lanes; group = chunk of 64 steps, lane = basis row. Chunk transfer
// matrices in LDS (bf16 + fp32 log-scale); wave 0 folds them.
//
// Round-8 lesson (counter-modeled): the scan is TOTAL-ISSUE-SLOT bound —
// LDS and VALU instructions cost the same per-wave issue slots; ~0.8 us per
// instruction/step at current occupancy. So: fp32 emission rows (no unpack),
// precomputed u16 index stream (no per-step context recurrence), and
// explicit one-step-ahead row pipelining (raise the ~52% issue utilization).
//
// Round-4 lesson: never clamp VGPRs below the live set (scratch spill).
// Round-5 lesson: 64-VGPR cliff matters at 2 blocks/CU (weights in SGPRs).
// Round-6 lesson: no dependent global loads in the body (all LDS).
// Round-7/8 lesson: don't trade 1 LDS inst for >1 VALU inst.
// Renorm every 8 steps is a PRECISION bound: emissions ~1/150 per step,
// 16-step windows would underflow fp32. Do not widen.
// ---------------------------------------------------------------------------

#define NSTATES 25
#define NLIVE   23
#define NFLAT   216
#define TLEN    2048
#define NSEQ    512
#define CHUNKS  32
#define CLEN    64

// ---------------------------------------------------------------------------
// Compile-time emission map: WMAP[state*216+flat] = k-index into wE,
// -1 = non-trainable (logit 1.0), -2 = absent. (Validated: absmax 0.0.)
// ---------------------------------------------------------------------------
struct WMap { short m[NSTATES * NFLAT]; };

constexpr WMap make_wmap() {
  WMap w{};
  for (int i = 0; i < NSTATES * NFLAT; i++) w.m[i] = -2;
  const unsigned char ST[29] = {0,1,2,3,4,5,6,7,8,9,10,11,11,12,12,12,13,
                                14,15,16,17,18,19,20,21,22,23,23,24};
  const unsigned char M1[29] = {0x1F,0x1F,0x1F,0x11,0x18,0x14,0x1F,0x1F,0x1F,
                                0x1F,0x0F,0x0F,0x0F,0x08,0x08,0x08,0x0F,
                                0x1F,0x1F,0x1F,0x1F,0x1F,0x1F,0x1F,0x1F,0x1F,
                                0x0F,0x0F,0x20};
  const unsigned char M2[29] = {0x1F,0x1F,0x11,0x18,0x14,0x1F,0x1F,0x1F,0x1F,
                                0x1F,0x0F,0x08,0x08,0x01,0x01,0x04,0x0F,
                                0x1F,0x1F,0x1F,0x1F,0x1F,0x1F,0x1F,0x1F,0x1F,
                                0x0F,0x20,0x20};
  const unsigned char M3[29] = {0x0F,0x01,0x08,0x04,0x0F,0x0F,0x0F,0x0F,0x0F,
                                0x0F,0x08,0x01,0x04,0x01,0x04,0x01,0x0F,
                                0x0F,0x0F,0x0F,0x0F,0x0F,0x0F,0x0F,0x0F,0x0F,
                                0x20,0x20,0x20};
  const unsigned char TR[29] = {1,1,1,0,1,1,1,1,1,1,1,1,1,0,0,0,1,
                                1,1,1,1,1,1,1,1,1,1,1,0};
  int k = 0;
  for (int s = 0; s < 29; s++) {
    for (int c1 = 0; c1 < 6; c1++) {
      if (!((M1[s] >> c1) & 1)) continue;
      for (int c2 = 0; c2 < 6; c2++) {
        if (!((M2[s] >> c2) & 1)) continue;
        if (c1 != 4 && c2 == 4) continue;  // pad-4 only as prefix (ORDER=2)
        for (int c3 = 0; c3 < 6; c3++) {
          if (!((M3[s] >> c3) & 1)) continue;
          w.m[ST[s] * NFLAT + c1 * 36 + c2 * 6 + c3] =
              TR[s] ? (short)(k++) : (short)-1;
        }
      }
    }
  }
  return w;
}
__device__ __constant__ WMap WMAP = make_wmap();

__device__ __forceinline__ unsigned short f2bf(float x) {  // RNE
  unsigned int u = __float_as_uint(x);
  u += 0x7fffu + ((u >> 16) & 1u);
  return (unsigned short)(u >> 16);
}

// ---------------------------------------------------------------------------
// One HMM step over the 23 live states, emission row already in registers.
// (n/o mapping validated rounds 3/5/6/7.)
// ---------------------------------------------------------------------------
__device__ __forceinline__ void hmm_step_r(float (&a)[NLIVE], const float (&w)[21],
                                           const float4 (&R)[6]) {
  float n0  = a[0]*w[0];
  float n1  = a[0]*w[1];
  float n4  = a[3]*w[2]  + a[16]*w[13];
  float n7  = a[3]*w[4]  + a[6]*w[6]  + a[19]*w[15];
  float n10 = a[3]*w[5]  + a[6]*w[8]  + a[9]*w[10] + a[22]*w[17];
  float n13 = a[12]      + a[13]*w[11];
  float n14 = a[3]*w[3]  + a[16]*w[14];
  float n17 = a[6]*w[7]  + a[19]*w[16];
  float n20 = a[9]*w[9]  + a[22]*w[18];
  float o2 = a[1],  o3 = a[2],  o5 = a[4],  o6 = a[5];
  float o8 = a[7],  o9 = a[8],  o11 = a[10], o12 = a[11];
  float o15 = a[14], o16 = a[15], o18 = a[17], o19 = a[18];
  float o21 = a[20], o22 = a[21];

  a[0]  = n0  * R[0].x;  a[1]  = n1  * R[0].y;
  a[2]  = o2  * R[0].z;  a[3]  = o3  * R[0].w;
  a[4]  = n4  * R[1].x;  a[5]  = o5  * R[1].y;
  a[6]  = o6  * R[1].z;  a[7]  = n7  * R[1].w;
  a[8]  = o8  * R[2].x;  a[9]  = o9  * R[2].y;
  a[10] = n10 * R[2].z;  a[11] = o11 * R[2].w;
  a[12] = o12 * R[3].x;  a[13] = n13 * R[3].y;
  a[14] = n14 * R[3].z;  a[15] = o15 * R[3].w;
  a[16] = o16 * R[4].x;  a[17] = n17 * R[4].y;
  a[18] = o18 * R[4].z;  a[19] = o19 * R[4].w;
  a[20] = n20 * R[5].x;  a[21] = o21 * R[5].y;
  a[22] = o22 * R[5].z;
}

__device__ __forceinline__ void renorm(float (&a)[NLIVE], float& L) {
  float s = (((a[0]+a[1])+(a[2]+a[3])) + ((a[4]+a[5])+(a[6]+a[7])))
          + (((a[8]+a[9])+(a[10]+a[11])) + ((a[12]+a[13])+(a[14]+a[15])))
          + (((a[16]+a[17])+(a[18]+a[19])) + ((a[20]+a[21])+a[22]));
  if (s > 0.0f) {
    L += __logf(s);
    float r = __fdividef(1.0f, s);
    #pragma unroll
    for (int j = 0; j < NLIVE; j++) a[j] *= r;
  } else {
    L = -3.0e38f;  // row died; stays dead
  }
}

// load one fp32 emission row (96 B, 6 x ds_read_b128) from byte offset
#define LDROW(R, off) do { const char* _p = (const char*)sEp + (off);          \
  R[0] = *(const float4*)(_p);      R[1] = *(const float4*)(_p + 16);          \
  R[2] = *(const float4*)(_p + 32); R[3] = *(const float4*)(_p + 48);          \
  R[4] = *(const float4*)(_p + 64); R[5] = *(const float4*)(_p + 80); } while(0)

// ---------------------------------------------------------------------------
// The whole problem in one kernel: block = one sequence.
// ---------------------------------------------------------------------------
__global__ __launch_bounds__(1024)
void hmm_kernel(const float* __restrict__ wT, const float* __restrict__ wE,
                const float* __restrict__ wI, const int* __restrict__ tokens,
                float* __restrict__ out) {
  __shared__ __align__(16) int            sTok[TLEN];              //  8192 B
  __shared__ __align__(16) unsigned short sIdx[TLEN];              //  4096 B
  __shared__ __align__(16) float          sEp[100 * 24];           //  9600 B
  __shared__ __align__(16) unsigned short sT[CHUNKS * NLIVE * 24]; // 35328 B
  __shared__ float sL[CHUNKS * NLIVE];                             //  2944 B
  __shared__ float sAW[24];
  __shared__ float sI[32];

  const int tid  = threadIdx.x;
  const int seq  = blockIdx.x;
  const int* trow = tokens + (size_t)seq * TLEN;

  // ---- stage tokens (fully coalesced: 8 B per thread) ----
  *(int2*)&sTok[2 * tid] = *(const int2*)(trow + 2 * tid);
  __syncthreads();

  // ---- precompute u16 byte-offset index stream (2 entries per thread) ----
  {
    const int t = 2 * tid;
    int pa0 = (t >= 2) ? sTok[t - 2] : 4;
    int pb0 = (t >= 1) ? sTok[t - 1] : 4;
    int i0 = ((pa0 * 5 + pb0) * 4 + sTok[t]) * 96;
    int pa1 = (t + 1 >= 2) ? sTok[t - 1] : 4;
    int pb1 = sTok[t];
    int i1 = ((pa1 * 5 + pb1) * 4 + sTok[t + 1]) * 96;
    ushort2 p; p.x = (unsigned short)i0; p.y = (unsigned short)i1;
    *(ushort2*)&sIdx[t] = p;
  }

  const int chunk = tid >> 5;
  const int row   = tid & 31;

  // ---- per-block setup into LDS (independent of sIdx; no barrier needed) --
  if (chunk < NSTATES) {
    const int st = chunk;
    float part = 0.0f;
    for (int c = row; c < NFLAT; c += 32) {
      short m = WMAP.m[st * NFLAT + c];
      if (m == -1) part += expf(1.0f);
      else if (m >= 0) part += expf(wE[m]);
    }
    #pragma unroll
    for (int m = 1; m < 32; m <<= 1) part += __shfl_xor(part, m, 32);
    float inv = 1.0f / part;
    for (int i = row; i < 100; i += 32) {
      int c12 = i >> 2, nt = i & 3;
      int p1 = c12 / 5, p2v = c12 - 5 * p1;
      int flat = p1 * 36 + p2v * 6 + nt;
      short m = WMAP.m[st * NFLAT + flat];
      float v = 0.0f;
      if (m == -1) v = expf(1.0f);
      else if (m >= 0) v = expf(wE[m]);
      sEp[i * 24 + st] = v * inv;
    }
  } else if (chunk == 25 && row == 0) {
    // softmax of multi-entry A rows -> 21 packed weights (validated)
    const float w0 = wT[0], w1 = wT[1], w2 = wT[2], w3 = wT[3], w4 = wT[4];
    const float w5 = wT[5], w6 = wT[6], w7 = wT[7], w8 = wT[8], w9 = wT[9];
    { float e0 = expf(1.0f - w0), e1 = expf(w0), is = 1.0f / (e0 + e1);
      sAW[0] = e0 * is; sAW[1] = e1 * is; }
    { float e4 = expf(w1), e14 = expf(w3);
      float e7 = expf(1.0f - w9 * w9), e10 = expf(1.0f - w9 * w9 * w9);
      float is = 1.0f / (e4 + e14 + e7 + e10);
      sAW[2] = e4 * is;  sAW[3] = e14 * is;
      sAW[4] = e7 * is;  sAW[5] = e10 * is; }
    { float e7 = expf(w2), e17 = expf(w4), e10 = expf(1.0f - w9 * w9);
      float is = 1.0f / (e7 + e17 + e10);
      sAW[6] = e7 * is; sAW[7] = e17 * is; sAW[8] = e10 * is; }
    { float e20 = expf(w5), e10 = expf(1.0f - w5), is = 1.0f / (e20 + e10);
      sAW[9] = e20 * is; sAW[10] = e10 * is; }
    sAW[11] = 0.5f; sAW[12] = 0.5f;   // row 13
    { float e4 = expf(w6), e14 = expf(1.0f - w6), is = 1.0f / (e4 + e14);
      sAW[13] = e4 * is; sAW[14] = e14 * is; }
    { float e7 = expf(w7), e17 = expf(1.0f - w7), is = 1.0f / (e7 + e17);
      sAW[15] = e7 * is; sAW[16] = e17 * is; }
    { float e10 = expf(w8), e20 = expf(1.0f - w8), is = 1.0f / (e10 + e20);
      sAW[17] = e10 * is; sAW[18] = e20 * is; }
    sAW[19] = 0.5f; sAW[20] = 0.5f;
  } else if (chunk == 25 && row == 1) {
    float e[9], s = 0.0f;
    for (int i = 0; i < 9; i++) { e[i] = expf(wI[i]); s += e[i]; }
    float inv = 1.0f / s;
    for (int i = 0; i < 9; i++) sI[i] = e[i] * inv;
    for (int i = 9; i < 32; i++) sI[i] = 0.0f;
  }
  __syncthreads();

  // A-weights: wave-uniform -> SGPRs
  float w[21];
  #pragma unroll
  for (int i = 0; i < 21; i++)
    w[i] = __uint_as_float(
        (unsigned)__builtin_amdgcn_readfirstlane(__float_as_uint(sAW[i])));

  // ---- scan: group = chunk of 64 steps, lane = basis row ----
  const int t0 = chunk * CLEN;

  float a[NLIVE];
  #pragma unroll
  for (int j = 0; j < NLIVE; j++) a[j] = 0.0f;
  if (row < NLIVE) a[row] = 1.0f;
  float L = 0.0f;

  float4 A[6], B[6];
  int b0 = 0;
  if (chunk == 0) {
    // body 0 = steps t = 1..7 (t = 0 is folded into the combine's init)
    uint4 iw = *(const uint4*)&sIdx[0];
    int o1 = iw.x >> 16;
    int o2 = iw.y & 0xffff, o3 = iw.y >> 16;
    int o4 = iw.z & 0xffff, o5 = iw.z >> 16;
    int o6 = iw.w & 0xffff, o7 = iw.w >> 16;
    LDROW(A, o1);
    LDROW(B, o2); hmm_step_r(a, w, A);
    LDROW(A, o3); hmm_step_r(a, w, B);
    LDROW(B, o4); hmm_step_r(a, w, A);
    LDROW(A, o5); hmm_step_r(a, w, B);
    LDROW(B, o6); hmm_step_r(a, w, A);
    LDROW(A, o7); hmm_step_r(a, w, B);
    hmm_step_r(a, w, A);
    renorm(a, L);
    b0 = 1;
  }

  for (int b = b0; b < CLEN / 8; b++) {
    uint4 iw = *(const uint4*)&sIdx[t0 + b * 8];
    int o0 = iw.x & 0xffff, o1 = iw.x >> 16;
    int o2 = iw.y & 0xffff, o3 = iw.y >> 16;
    int o4 = iw.z & 0xffff, o5 = iw.z >> 16;
    int o6 = iw.w & 0xffff, o7 = iw.w >> 16;
    LDROW(A, o0);
    LDROW(B, o1); hmm_step_r(a, w, A);
    LDROW(A, o2); hmm_step_r(a, w, B);
    LDROW(B, o3); hmm_step_r(a, w, A);
    LDROW(A, o4); hmm_step_r(a, w, B);
    LDROW(B, o5); hmm_step_r(a, w, A);
    LDROW(A, o6); hmm_step_r(a, w, B);
    LDROW(B, o7); hmm_step_r(a, w, A);
    hmm_step_r(a, w, B);
    renorm(a, L);
  }

  // stash chunk matrix row in LDS (bf16 values, fp32 L)
  if (row < NLIVE) {
    const int base = (chunk * NLIVE + row) * 24;
    #pragma unroll
    for (int k = 0; k < 11; k++) {
      ushort2 p; p.x = f2bf(a[2 * k]); p.y = f2bf(a[2 * k + 1]);
      *(ushort2*)&sT[base + 2 * k] = p;
    }
    { ushort2 p; p.x = f2bf(a[22]); p.y = 0; *(ushort2*)&sT[base + 22] = p; }
    sL[chunk * NLIVE + row] = L;
  }
  __syncthreads();

  // ---- combine (wave 0 only): fold 32 chunk matrices, lane j = column j ----
  if (tid < 64) {
    const int lane = tid;
    const bool act = (lane < NLIVE);
    const int jc   = act ? lane : 0;

    const unsigned off0 = sIdx[0];   // byte offset of row (4,4,tok0)
    float e0j = *(const float*)((const char*)sEp + off0 + 4 * jc);
    float v = act ? sI[lane] * e0j : 0.0f;
    float s = v;
    #pragma unroll
    for (int m = 1; m < 32; m <<= 1) s += __shfl_xor(s, m, 32);
    float ll = __logf(s);
    v = act ? v * __fdividef(1.0f, s) : 0.0f;

    for (int c = 0; c < CHUNKS; c++) {
      float Lj  = act ? sL[c * NLIVE + lane] : -3.0e38f;
      float key = (act && v > 0.0f) ? Lj : -3.0e38f;
      float mx = key;
      #pragma unroll
      for (int m = 1; m < 32; m <<= 1) mx = fmaxf(mx, __shfl_xor(mx, m, 32));
      float wgt = (act && v > 0.0f) ? v * __expf(Lj - mx) : 0.0f;

      float nv = 0.0f;
      #pragma unroll
      for (int r = 0; r < NLIVE; r++) {
        float wr = __shfl(wgt, r, 64);
        nv += wr * __uint_as_float(((unsigned)sT[(c * NLIVE + r) * 24 + jc]) << 16);
      }
      float nva = act ? nv : 0.0f;
      float s2 = nva;
      #pragma unroll
      for (int m = 1; m < 32; m <<= 1) s2 += __shfl_xor(s2, m, 32);
      ll += mx + __logf(s2);
      v = act ? nv * __fdividef(1.0f, s2) : 0.0f;
    }

    if (lane == 0) out[seq] = ll;
  }
}

// ---------------------------------------------------------------------------
extern "C" void kernel_launch(void* const* d_in, const int* in_sizes, int n_in,
                              void* d_out, int out_size, void* d_ws, size_t ws_size,
                              hipStream_t stream) {
  const float* wT = (const float*)d_in[0];   // transition_kernel (10)
  const float* wE = (const float*)d_in[1];   // emission_kernel (5400)
  const float* wI = (const float*)d_in[2];   // init_kernel (25)
  const int* tokens = (const int*)d_in[3];   // (512, 2048) int32
  float* out = (float*)d_out;                // (512,) float32
  (void)d_ws; (void)ws_size;                 // workspace unused

  hmm_kernel<<<NSEQ, 1024, 0, stream>>>(wT, wE, wI, tokens, out);
}

// Round 10
// 138.245 us; speedup vs baseline: 1.3445x; 1.2655x over previous
//
#include <hip/hip_runtime.h>
#include <hip/hip_bf16.h>
#include <math.h>

// ---------------------------------------------------------------------------
// CgpHmmCell forward: 512 seqs x 2048 steps x 25-state HMM (23 live states;
// states 23/24 emit only 'X' which never occurs in tokens in [0,4)).
//
// ROUND-10: revert to the empirically fastest scan shape (round 5: 512-thread
// blocks, 16 groups x 32 lanes, CLEN=128, GLOBAL token int4 loads with
// distance-1 prefetch, fp32 pitch-32 emission rows in LDS) and fuse the tiny
// setup into each block (round-7-proven) so the whole problem is ONE kernel.
//
// Empirical record (kernel time, same total work):
//   R3/R5 shape (16 waves/CU, global tokens): 74 / 94 us
//   R6-R9 shape (32 waves/CU, LDS tokens):   121-135 us  <- never beat R5
//
// Lessons enforced here:
//   R4: never clamp VGPRs below the live set (scratch spill disaster).
//   R5: stay at/below the 64-VGPR occupancy cliff (A-weights -> SGPRs).
//   R6: keep the distance-1 token prefetch (exposed dependent load = -30%).
//   R7/8: don't trade 1 LDS inst for >1 VALU inst (bf16 rows regressed).
//   Renorm every 8 steps is a PRECISION bound (emissions ~1/150 per step;
//   16-step windows would underflow fp32). Do not widen.
// ---------------------------------------------------------------------------

#define NSTATES 25
#define NLIVE   23
#define NFLAT   216
#define NPACK   100
#define TLEN    2048
#define NSEQ    512
#define CHUNKS  16
#define CLEN    128

// ---------------------------------------------------------------------------
// Compile-time emission map: WMAP[state*216+flat] = k-index into wE,
// -1 = non-trainable (logit 1.0), -2 = absent. (Validated: absmax 0.0.)
// ---------------------------------------------------------------------------
struct WMap { short m[NSTATES * NFLAT]; };

constexpr WMap make_wmap() {
  WMap w{};
  for (int i = 0; i < NSTATES * NFLAT; i++) w.m[i] = -2;
  const unsigned char ST[29] = {0,1,2,3,4,5,6,7,8,9,10,11,11,12,12,12,13,
                                14,15,16,17,18,19,20,21,22,23,23,24};
  const unsigned char M1[29] = {0x1F,0x1F,0x1F,0x11,0x18,0x14,0x1F,0x1F,0x1F,
                                0x1F,0x0F,0x0F,0x0F,0x08,0x08,0x08,0x0F,
                                0x1F,0x1F,0x1F,0x1F,0x1F,0x1F,0x1F,0x1F,0x1F,
                                0x0F,0x0F,0x20};
  const unsigned char M2[29] = {0x1F,0x1F,0x11,0x18,0x14,0x1F,0x1F,0x1F,0x1F,
                                0x1F,0x0F,0x08,0x08,0x01,0x01,0x04,0x0F,
                                0x1F,0x1F,0x1F,0x1F,0x1F,0x1F,0x1F,0x1F,0x1F,
                                0x0F,0x20,0x20};
  const unsigned char M3[29] = {0x0F,0x01,0x08,0x04,0x0F,0x0F,0x0F,0x0F,0x0F,
                                0x0F,0x08,0x01,0x04,0x01,0x04,0x01,0x0F,
                                0x0F,0x0F,0x0F,0x0F,0x0F,0x0F,0x0F,0x0F,0x0F,
                                0x20,0x20,0x20};
  const unsigned char TR[29] = {1,1,1,0,1,1,1,1,1,1,1,1,1,0,0,0,1,
                                1,1,1,1,1,1,1,1,1,1,1,0};
  int k = 0;
  for (int s = 0; s < 29; s++) {
    for (int c1 = 0; c1 < 6; c1++) {
      if (!((M1[s] >> c1) & 1)) continue;
      for (int c2 = 0; c2 < 6; c2++) {
        if (!((M2[s] >> c2) & 1)) continue;
        if (c1 != 4 && c2 == 4) continue;  // pad-4 only as prefix (ORDER=2)
        for (int c3 = 0; c3 < 6; c3++) {
          if (!((M3[s] >> c3) & 1)) continue;
          w.m[ST[s] * NFLAT + c1 * 36 + c2 * 6 + c3] =
              TR[s] ? (short)(k++) : (short)-1;
        }
      }
    }
  }
  return w;
}
__device__ __constant__ WMap WMAP = make_wmap();

__device__ __forceinline__ unsigned short f2bf(float x) {  // RNE
  unsigned int u = __float_as_uint(x);
  u += 0x7fffu + ((u >> 16) & 1u);
  return (unsigned short)(u >> 16);
}

// ---------------------------------------------------------------------------
// One HMM step over the 23 live states (validated rounds 3/5/6/7).
// idx = packed emission index (c12*4+nt), uniform within the 32-lane group.
// sBt pitch = 32 floats -> 6 ds_read_b128, zero bank conflicts (R5-measured).
// ---------------------------------------------------------------------------
__device__ __forceinline__ void hmm_step(float (&a)[NLIVE], const float (&w)[21],
                                         const float* __restrict__ bt, int idx) {
  const float* er = bt + (idx << 5);
  float4 e0 = *(const float4*)(er + 0);
  float4 e1 = *(const float4*)(er + 4);
  float4 e2 = *(const float4*)(er + 8);
  float4 e3 = *(const float4*)(er + 12);
  float4 e4 = *(const float4*)(er + 16);
  float4 e5 = *(const float4*)(er + 20);

  float n0  = a[0]*w[0];
  float n1  = a[0]*w[1];
  float n4  = a[3]*w[2]  + a[16]*w[13];
  float n7  = a[3]*w[4]  + a[6]*w[6]  + a[19]*w[15];
  float n10 = a[3]*w[5]  + a[6]*w[8]  + a[9]*w[10] + a[22]*w[17];
  float n13 = a[12]      + a[13]*w[11];
  float n14 = a[3]*w[3]  + a[16]*w[14];
  float n17 = a[6]*w[7]  + a[19]*w[16];
  float n20 = a[9]*w[9]  + a[22]*w[18];
  float o2 = a[1],  o3 = a[2],  o5 = a[4],  o6 = a[5];
  float o8 = a[7],  o9 = a[8],  o11 = a[10], o12 = a[11];
  float o15 = a[14], o16 = a[15], o18 = a[17], o19 = a[18];
  float o21 = a[20], o22 = a[21];

  a[0] = n0 * e0.x;  a[1] = n1 * e0.y;  a[2] = o2 * e0.z;  a[3] = o3 * e0.w;
  a[4] = n4 * e1.x;  a[5] = o5 * e1.y;  a[6] = o6 * e1.z;  a[7] = n7 * e1.w;
  a[8] = o8 * e2.x;  a[9] = o9 * e2.y;  a[10] = n10 * e2.z; a[11] = o11 * e2.w;
  a[12] = o12 * e3.x; a[13] = n13 * e3.y; a[14] = n14 * e3.z; a[15] = o15 * e3.w;
  a[16] = o16 * e4.x; a[17] = n17 * e4.y; a[18] = o18 * e4.z; a[19] = o19 * e4.w;
  a[20] = n20 * e5.x; a[21] = o21 * e5.y; a[22] = o22 * e5.z;
}

__device__ __forceinline__ void renorm(float (&a)[NLIVE], float& L) {
  float s = (((a[0]+a[1])+(a[2]+a[3])) + ((a[4]+a[5])+(a[6]+a[7])))
          + (((a[8]+a[9])+(a[10]+a[11])) + ((a[12]+a[13])+(a[14]+a[15])))
          + (((a[16]+a[17])+(a[18]+a[19])) + ((a[20]+a[21])+a[22]));
  if (s > 0.0f) {
    L += __logf(s);
    float r = __fdividef(1.0f, s);
    #pragma unroll
    for (int j = 0; j < NLIVE; j++) a[j] *= r;
  } else {
    L = -3.0e38f;  // row died; stays dead
  }
}

// context update: consume token nt. idx = c12*4+nt; c12' = p2*5+nt; p2' = nt.
#define STEP(nt_) { int nt = (nt_); hmm_step(a, w, sBt, (c12 << 2) + nt); \
                    c12 = p2 * 5 + nt; p2 = nt; }

// ---------------------------------------------------------------------------
// The whole problem in one kernel: block = one sequence, 512 threads =
// 16 groups x 32 lanes; group = chunk of 128 steps, lane = basis row.
// ---------------------------------------------------------------------------
__global__ __launch_bounds__(512)
void hmm_kernel(const float* __restrict__ wT, const float* __restrict__ wE,
                const float* __restrict__ wI, const int* __restrict__ tokens,
                float* __restrict__ out) {
  __shared__ __align__(16) float          sBt[NPACK * 32];          // 12800 B
  __shared__ __align__(16) unsigned short sT[CHUNKS * NLIVE * 24];  // 17664 B
  __shared__ float sL[CHUNKS * NLIVE];                              //  1472 B
  __shared__ float sAW[24];
  __shared__ float sI[32];

  const int tid   = threadIdx.x;
  const int seq   = blockIdx.x;
  const int chunk = tid >> 5;
  const int row   = tid & 31;
  const int* trow = tokens + (size_t)seq * TLEN;

  // ---- per-block setup into LDS (16 groups cover 25 states in 2 passes) ---
  for (int st = chunk; st < NSTATES; st += 16) {
    float part = 0.0f;
    for (int c = row; c < NFLAT; c += 32) {
      short m = WMAP.m[st * NFLAT + c];
      if (m == -1) part += expf(1.0f);
      else if (m >= 0) part += expf(wE[m]);
    }
    #pragma unroll
    for (int m = 1; m < 32; m <<= 1) part += __shfl_xor(part, m, 32);
    float inv = 1.0f / part;
    for (int i = row; i < NPACK; i += 32) {
      int c12 = i >> 2, nt = i & 3;
      int p1 = c12 / 5, p2v = c12 - 5 * p1;
      int flat = p1 * 36 + p2v * 6 + nt;
      short m = WMAP.m[st * NFLAT + flat];
      float v = 0.0f;
      if (m == -1) v = expf(1.0f);
      else if (m >= 0) v = expf(wE[m]);
      sBt[i * 32 + st] = v * inv;
    }
  }
  if (tid == 480) {
    // softmax of multi-entry A rows -> 21 packed weights (validated)
    const float w0 = wT[0], w1 = wT[1], w2 = wT[2], w3 = wT[3], w4 = wT[4];
    const float w5 = wT[5], w6 = wT[6], w7 = wT[7], w8 = wT[8], w9 = wT[9];
    { float e0 = expf(1.0f - w0), e1 = expf(w0), is = 1.0f / (e0 + e1);
      sAW[0] = e0 * is; sAW[1] = e1 * is; }
    { float e4 = expf(w1), e14 = expf(w3);
      float e7 = expf(1.0f - w9 * w9), e10 = expf(1.0f - w9 * w9 * w9);
      float is = 1.0f / (e4 + e14 + e7 + e10);
      sAW[2] = e4 * is;  sAW[3] = e14 * is;
      sAW[4] = e7 * is;  sAW[5] = e10 * is; }
    { float e7 = expf(w2), e17 = expf(w4), e10 = expf(1.0f - w9 * w9);
      float is = 1.0f / (e7 + e17 + e10);
      sAW[6] = e7 * is; sAW[7] = e17 * is; sAW[8] = e10 * is; }
    { float e20 = expf(w5), e10 = expf(1.0f - w5), is = 1.0f / (e20 + e10);
      sAW[9] = e20 * is; sAW[10] = e10 * is; }
    sAW[11] = 0.5f; sAW[12] = 0.5f;   // row 13
    { float e4 = expf(w6), e14 = expf(1.0f - w6), is = 1.0f / (e4 + e14);
      sAW[13] = e4 * is; sAW[14] = e14 * is; }
    { float e7 = expf(w7), e17 = expf(1.0f - w7), is = 1.0f / (e7 + e17);
      sAW[15] = e7 * is; sAW[16] = e17 * is; }
    { float e10 = expf(w8), e20 = expf(1.0f - w8), is = 1.0f / (e10 + e20);
      sAW[17] = e10 * is; sAW[18] = e20 * is; }
    sAW[19] = 0.5f; sAW[20] = 0.5f;
  } else if (tid == 481) {
    float e[9], s = 0.0f;
    for (int i = 0; i < 9; i++) { e[i] = expf(wI[i]); s += e[i]; }
    float inv = 1.0f / s;
    for (int i = 0; i < 9; i++) sI[i] = e[i] * inv;
    for (int i = 9; i < 32; i++) sI[i] = 0.0f;
  }
  __syncthreads();

  // A-weights: wave-uniform -> SGPRs (R6-proven)
  float w[21];
  #pragma unroll
  for (int i = 0; i < 21; i++)
    w[i] = __uint_as_float(
        (unsigned)__builtin_amdgcn_readfirstlane(__float_as_uint(sAW[i])));

  // ---- scan: group = chunk of 128 steps, lane = basis row ----
  const int t0 = chunk * CLEN;

  float a[NLIVE];
  #pragma unroll
  for (int j = 0; j < NLIVE; j++) a[j] = 0.0f;
  if (row < NLIVE) a[row] = 1.0f;
  float L = 0.0f;

  int c12, p2;
  int4 q0 = *(const int4*)(trow + t0);
  int4 q1 = *(const int4*)(trow + t0 + 4);

  int b = 0;
  if (chunk == 0) {
    // body 0 = steps t = 1..7 (t = 0 is folded into the combine's init)
    c12 = 20 + q0.x; p2 = q0.x;   // context (4, tok0)
    STEP(q0.y); STEP(q0.z); STEP(q0.w);
    STEP(q1.x); STEP(q1.y); STEP(q1.z); STEP(q1.w);
    renorm(a, L);
    b = 1;
    q0 = *(const int4*)(trow + 8);
    q1 = *(const int4*)(trow + 12);
  } else {
    int2 pp = *(const int2*)(trow + t0 - 2);   // 8B-aligned (t0 mult of 128)
    c12 = pp.x * 5 + pp.y; p2 = pp.y;
  }

  for (; b < CLEN / 8; b++) {
    int4 n0 = q0, n1 = q1;
    if (b + 1 < CLEN / 8) {               // distance-1 GLOBAL token prefetch
      n0 = *(const int4*)(trow + t0 + (b + 1) * 8);
      n1 = *(const int4*)(trow + t0 + (b + 1) * 8 + 4);
    }
    STEP(q0.x); STEP(q0.y); STEP(q0.z); STEP(q0.w);
    STEP(q1.x); STEP(q1.y); STEP(q1.z); STEP(q1.w);
    renorm(a, L);
    q0 = n0; q1 = n1;
  }

  // stash chunk matrix row in LDS (bf16 values, fp32 L)
  if (row < NLIVE) {
    const int base = (chunk * NLIVE + row) * 24;
    #pragma unroll
    for (int k = 0; k < 11; k++) {
      ushort2 p; p.x = f2bf(a[2 * k]); p.y = f2bf(a[2 * k + 1]);
      *(ushort2*)&sT[base + 2 * k] = p;
    }
    { ushort2 p; p.x = f2bf(a[22]); p.y = 0; *(ushort2*)&sT[base + 22] = p; }
    sL[chunk * NLIVE + row] = L;
  }
  __syncthreads();

  // ---- combine (wave 0 only): fold 16 chunk matrices, lane j = column j ----
  if (tid < 64) {
    const int lane = tid;
    const bool act = (lane < NLIVE);
    const int jc   = act ? lane : 0;

    const int tok0 = trow[0];
    const int idx0 = 96 + tok0;   // packed (4,4,tok0)

    float v = act ? sI[lane] * sBt[idx0 * 32 + lane] : 0.0f;
    float s = v;
    #pragma unroll
    for (int m = 1; m < 32; m <<= 1) s += __shfl_xor(s, m, 32);
    float ll = __logf(s);
    v = act ? v * __fdividef(1.0f, s) : 0.0f;

    for (int c = 0; c < CHUNKS; c++) {
      float Lj  = act ? sL[c * NLIVE + lane] : -3.0e38f;
      float key = (act && v > 0.0f) ? Lj : -3.0e38f;
      float mx = key;
      #pragma unroll
      for (int m = 1; m < 32; m <<= 1) mx = fmaxf(mx, __shfl_xor(mx, m, 32));
      float wgt = (act && v > 0.0f) ? v * __expf(Lj - mx) : 0.0f;

      float nv = 0.0f;
      #pragma unroll
      for (int r = 0; r < NLIVE; r++) {
        float wr = __shfl(wgt, r, 64);
        nv += wr * __uint_as_float(((unsigned)sT[(c * NLIVE + r) * 24 + jc]) << 16);
      }
      float nva = act ? nv : 0.0f;
      float s2 = nva;
      #pragma unroll
      for (int m = 1; m < 32; m <<= 1) s2 += __shfl_xor(s2, m, 32);
      ll += mx + __logf(s2);
      v = act ? nv * __fdividef(1.0f, s2) : 0.0f;
    }

    if (lane == 0) out[seq] = ll;
  }
}

// ---------------------------------------------------------------------------
extern "C" void kernel_launch(void* const* d_in, const int* in_sizes, int n_in,
                              void* d_out, int out_size, void* d_ws, size_t ws_size,
                              hipStream_t stream) {
  const float* wT = (const float*)d_in[0];   // transition_kernel (10)
  const float* wE = (const float*)d_in[1];   // emission_kernel (5400)
  const float* wI = (const float*)d_in[2];   // init_kernel (25)
  const int* tokens = (const int*)d_in[3];   // (512, 2048) int32
  float* out = (float*)d_out;                // (512,) float32
  (void)d_ws; (void)ws_size;                 // workspace unused

  hmm_kernel<<<NSEQ, 512, 0, stream>>>(wT, wE, wI, tokens, out);
}

// Round 11
// 134.901 us; speedup vs baseline: 1.3779x; 1.0248x over previous
//
#include <hip/hip_runtime.h>
#include <hip/hip_bf16.h>
#include <math.h>

// ---------------------------------------------------------------------------
// CgpHmmCell forward: 512 seqs x 2048 steps x 25-state HMM (23 live states;
// states 23/24 emit only 'X' which never occurs in tokens in [0,4)).
//
// ROUND-11 = R10 winner (one kernel, block=sequence, 512 thr = 16 groups x
// 32 lanes, CLEN=128, global token int4 + distance-1 prefetch, fp32 pitch-32
// emission rows in LDS, bf16 chunk matrices, wave-0 combine) plus:
//   (a) one-step-ahead emission-row pipelining (ping-pong A/B float4[6]).
//       KEY: at 512 blocks = 2 blocks/CU, occupancy only needs VGPR <= 128,
//       so the 64-VGPR "cliff" enforced since R5 was irrelevant — register-
//       heavy pipelining is free. __launch_bounds__(512,4) caps at 128.
//   (b) renorm every 16 steps (was 8), enabled by prescaling the emission
//       table by 16 (exponent-exact): drift <= 16^16 = e^44 between renorms,
//       well inside fp32 (+-e^88). L -= steps*log16 at chunk end; combine
//       init ll -= log16. Halves renorm cost and serial log/div stalls.
//
// Lessons enforced: R4 never clamp VGPR below live set; R6 keep token
// prefetch; R7/8 don't trade 1 LDS inst for >1 VALU inst.
// ---------------------------------------------------------------------------

#define NSTATES 25
#define NLIVE   23
#define NFLAT   216
#define NPACK   100
#define TLEN    2048
#define NSEQ    512
#define CHUNKS  16
#define CLEN    128

#define LOG16 2.772588722239781f

// ---------------------------------------------------------------------------
// Compile-time emission map: WMAP[state*216+flat] = k-index into wE,
// -1 = non-trainable (logit 1.0), -2 = absent. (Validated: absmax 0.0.)
// ---------------------------------------------------------------------------
struct WMap { short m[NSTATES * NFLAT]; };

constexpr WMap make_wmap() {
  WMap w{};
  for (int i = 0; i < NSTATES * NFLAT; i++) w.m[i] = -2;
  const unsigned char ST[29] = {0,1,2,3,4,5,6,7,8,9,10,11,11,12,12,12,13,
                                14,15,16,17,18,19,20,21,22,23,23,24};
  const unsigned char M1[29] = {0x1F,0x1F,0x1F,0x11,0x18,0x14,0x1F,0x1F,0x1F,
                                0x1F,0x0F,0x0F,0x0F,0x08,0x08,0x08,0x0F,
                                0x1F,0x1F,0x1F,0x1F,0x1F,0x1F,0x1F,0x1F,0x1F,
                                0x0F,0x0F,0x20};
  const unsigned char M2[29] = {0x1F,0x1F,0x11,0x18,0x14,0x1F,0x1F,0x1F,0x1F,
                                0x1F,0x0F,0x08,0x08,0x01,0x01,0x04,0x0F,
                                0x1F,0x1F,0x1F,0x1F,0x1F,0x1F,0x1F,0x1F,0x1F,
                                0x0F,0x20,0x20};
  const unsigned char M3[29] = {0x0F,0x01,0x08,0x04,0x0F,0x0F,0x0F,0x0F,0x0F,
                                0x0F,0x08,0x01,0x04,0x01,0x04,0x01,0x0F,
                                0x0F,0x0F,0x0F,0x0F,0x0F,0x0F,0x0F,0x0F,0x0F,
                                0x20,0x20,0x20};
  const unsigned char TR[29] = {1,1,1,0,1,1,1,1,1,1,1,1,1,0,0,0,1,
                                1,1,1,1,1,1,1,1,1,1,1,0};
  int k = 0;
  for (int s = 0; s < 29; s++) {
    for (int c1 = 0; c1 < 6; c1++) {
      if (!((M1[s] >> c1) & 1)) continue;
      for (int c2 = 0; c2 < 6; c2++) {
        if (!((M2[s] >> c2) & 1)) continue;
        if (c1 != 4 && c2 == 4) continue;  // pad-4 only as prefix (ORDER=2)
        for (int c3 = 0; c3 < 6; c3++) {
          if (!((M3[s] >> c3) & 1)) continue;
          w.m[ST[s] * NFLAT + c1 * 36 + c2 * 6 + c3] =
              TR[s] ? (short)(k++) : (short)-1;
        }
      }
    }
  }
  return w;
}
__device__ __constant__ WMap WMAP = make_wmap();

__device__ __forceinline__ unsigned short f2bf(float x) {  // RNE
  unsigned int u = __float_as_uint(x);
  u += 0x7fffu + ((u >> 16) & 1u);
  return (unsigned short)(u >> 16);
}

// ---------------------------------------------------------------------------
// Load one fp32 emission row (pitch 32) into registers; 6 ds_read_b128.
// ---------------------------------------------------------------------------
__device__ __forceinline__ void ldrow(float4 (&R)[6],
                                      const float* __restrict__ bt, int idx) {
  const float4* er = (const float4*)(bt + (idx << 5));
  R[0] = er[0]; R[1] = er[1]; R[2] = er[2];
  R[3] = er[3]; R[4] = er[4]; R[5] = er[5];
}

// ---------------------------------------------------------------------------
// One HMM step over the 23 live states, emission row already in registers
// (n/o mapping validated rounds 3/5/6/7/9/10).
// ---------------------------------------------------------------------------
__device__ __forceinline__ void hmm_step_r(float (&a)[NLIVE], const float (&w)[21],
                                           const float4 (&R)[6]) {
  float n0  = a[0]*w[0];
  float n1  = a[0]*w[1];
  float n4  = a[3]*w[2]  + a[16]*w[13];
  float n7  = a[3]*w[4]  + a[6]*w[6]  + a[19]*w[15];
  float n10 = a[3]*w[5]  + a[6]*w[8]  + a[9]*w[10] + a[22]*w[17];
  float n13 = a[12]      + a[13]*w[11];
  float n14 = a[3]*w[3]  + a[16]*w[14];
  float n17 = a[6]*w[7]  + a[19]*w[16];
  float n20 = a[9]*w[9]  + a[22]*w[18];
  float o2 = a[1],  o3 = a[2],  o5 = a[4],  o6 = a[5];
  float o8 = a[7],  o9 = a[8],  o11 = a[10], o12 = a[11];
  float o15 = a[14], o16 = a[15], o18 = a[17], o19 = a[18];
  float o21 = a[20], o22 = a[21];

  a[0]  = n0  * R[0].x;  a[1]  = n1  * R[0].y;
  a[2]  = o2  * R[0].z;  a[3]  = o3  * R[0].w;
  a[4]  = n4  * R[1].x;  a[5]  = o5  * R[1].y;
  a[6]  = o6  * R[1].z;  a[7]  = n7  * R[1].w;
  a[8]  = o8  * R[2].x;  a[9]  = o9  * R[2].y;
  a[10] = n10 * R[2].z;  a[11] = o11 * R[2].w;
  a[12] = o12 * R[3].x;  a[13] = n13 * R[3].y;
  a[14] = n14 * R[3].z;  a[15] = o15 * R[3].w;
  a[16] = o16 * R[4].x;  a[17] = n17 * R[4].y;
  a[18] = o18 * R[4].z;  a[19] = o19 * R[4].w;
  a[20] = n20 * R[5].x;  a[21] = o21 * R[5].y;
  a[22] = o22 * R[5].z;
}

__device__ __forceinline__ void renorm(float (&a)[NLIVE], float& L) {
  float s = (((a[0]+a[1])+(a[2]+a[3])) + ((a[4]+a[5])+(a[6]+a[7])))
          + (((a[8]+a[9])+(a[10]+a[11])) + ((a[12]+a[13])+(a[14]+a[15])))
          + (((a[16]+a[17])+(a[18]+a[19])) + ((a[20]+a[21])+a[22]));
  if (s > 0.0f) {
    L += __logf(s);
    float r = __fdividef(1.0f, s);
    #pragma unroll
    for (int j = 0; j < NLIVE; j++) a[j] *= r;
  } else {
    L = -3.0e38f;  // row died; stays dead
  }
}

// pipelined macros: load row for the NEXT step, then compute the CURRENT one
#define LDONLY(Rn, nt_) { int nt = (nt_); ldrow(Rn, sBt, (c12 << 2) + nt); \
                          c12 = p2 * 5 + nt; p2 = nt; }
#define LDSTEP(Rn, Rc, nt_) { int nt = (nt_); ldrow(Rn, sBt, (c12 << 2) + nt); \
                              c12 = p2 * 5 + nt; p2 = nt; hmm_step_r(a, w, Rc); }

// ---------------------------------------------------------------------------
// The whole problem in one kernel: block = one sequence, 512 threads =
// 16 groups x 32 lanes; group = chunk of 128 steps, lane = basis row.
// __launch_bounds__(512,4): cap VGPR at 128 = exactly the 2-blocks/CU need.
// ---------------------------------------------------------------------------
__global__ __launch_bounds__(512, 4)
void hmm_kernel(const float* __restrict__ wT, const float* __restrict__ wE,
                const float* __restrict__ wI, const int* __restrict__ tokens,
                float* __restrict__ out) {
  __shared__ __align__(16) float          sBt[NPACK * 32];          // 12800 B
  __shared__ __align__(16) unsigned short sT[CHUNKS * NLIVE * 24];  // 17664 B
  __shared__ float sL[CHUNKS * NLIVE];                              //  1472 B
  __shared__ float sAW[24];
  __shared__ float sI[32];

  const int tid   = threadIdx.x;
  const int seq   = blockIdx.x;
  const int chunk = tid >> 5;
  const int row   = tid & 31;
  const int* trow = tokens + (size_t)seq * TLEN;

  // ---- per-block setup into LDS (16 groups cover 25 states in 2 passes) ---
  // Emission rows PRESCALED by 16 (exponent-exact).
  for (int st = chunk; st < NSTATES; st += 16) {
    float part = 0.0f;
    for (int c = row; c < NFLAT; c += 32) {
      short m = WMAP.m[st * NFLAT + c];
      if (m == -1) part += expf(1.0f);
      else if (m >= 0) part += expf(wE[m]);
    }
    #pragma unroll
    for (int m = 1; m < 32; m <<= 1) part += __shfl_xor(part, m, 32);
    float inv = 16.0f / part;
    for (int i = row; i < NPACK; i += 32) {
      int c12 = i >> 2, nt = i & 3;
      int p1 = c12 / 5, p2v = c12 - 5 * p1;
      int flat = p1 * 36 + p2v * 6 + nt;
      short m = WMAP.m[st * NFLAT + flat];
      float v = 0.0f;
      if (m == -1) v = expf(1.0f);
      else if (m >= 0) v = expf(wE[m]);
      sBt[i * 32 + st] = v * inv;
    }
  }
  if (tid == 480) {
    // softmax of multi-entry A rows -> 21 packed weights (validated)
    const float w0 = wT[0], w1 = wT[1], w2 = wT[2], w3 = wT[3], w4 = wT[4];
    const float w5 = wT[5], w6 = wT[6], w7 = wT[7], w8 = wT[8], w9 = wT[9];
    { float e0 = expf(1.0f - w0), e1 = expf(w0), is = 1.0f / (e0 + e1);
      sAW[0] = e0 * is; sAW[1] = e1 * is; }
    { float e4 = expf(w1), e14 = expf(w3);
      float e7 = expf(1.0f - w9 * w9), e10 = expf(1.0f - w9 * w9 * w9);
      float is = 1.0f / (e4 + e14 + e7 + e10);
      sAW[2] = e4 * is;  sAW[3] = e14 * is;
      sAW[4] = e7 * is;  sAW[5] = e10 * is; }
    { float e7 = expf(w2), e17 = expf(w4), e10 = expf(1.0f - w9 * w9);
      float is = 1.0f / (e7 + e17 + e10);
      sAW[6] = e7 * is; sAW[7] = e17 * is; sAW[8] = e10 * is; }
    { float e20 = expf(w5), e10 = expf(1.0f - w5), is = 1.0f / (e20 + e10);
      sAW[9] = e20 * is; sAW[10] = e10 * is; }
    sAW[11] = 0.5f; sAW[12] = 0.5f;   // row 13
    { float e4 = expf(w6), e14 = expf(1.0f - w6), is = 1.0f / (e4 + e14);
      sAW[13] = e4 * is; sAW[14] = e14 * is; }
    { float e7 = expf(w7), e17 = expf(1.0f - w7), is = 1.0f / (e7 + e17);
      sAW[15] = e7 * is; sAW[16] = e17 * is; }
    { float e10 = expf(w8), e20 = expf(1.0f - w8), is = 1.0f / (e10 + e20);
      sAW[17] = e10 * is; sAW[18] = e20 * is; }
    sAW[19] = 0.5f; sAW[20] = 0.5f;
  } else if (tid == 481) {
    float e[9], s = 0.0f;
    for (int i = 0; i < 9; i++) { e[i] = expf(wI[i]); s += e[i]; }
    float inv = 1.0f / s;
    for (int i = 0; i < 9; i++) sI[i] = e[i] * inv;
    for (int i = 9; i < 32; i++) sI[i] = 0.0f;
  }
  __syncthreads();

  // A-weights: wave-uniform -> SGPRs
  float w[21];
  #pragma unroll
  for (int i = 0; i < 21; i++)
    w[i] = __uint_as_float(
        (unsigned)__builtin_amdgcn_readfirstlane(__float_as_uint(sAW[i])));

  // ---- scan: group = chunk of 128 steps, lane = basis row ----
  const int t0 = chunk * CLEN;

  float a[NLIVE];
  #pragma unroll
  for (int j = 0; j < NLIVE; j++) a[j] = 0.0f;
  if (row < NLIVE) a[row] = 1.0f;
  float L = 0.0f;

  float4 A[6], B[6];
  int c12, p2;
  int4 q0 = *(const int4*)(trow + t0);
  int4 q1 = *(const int4*)(trow + t0 + 4);

  int b = 0;
  if (chunk == 0) {
    // body 0 = steps t = 1..7 (t = 0 is folded into the combine's init)
    c12 = 20 + q0.x; p2 = q0.x;   // context (4, tok0)
    LDONLY(A, q0.y);
    LDSTEP(B, A, q0.z);
    LDSTEP(A, B, q0.w);
    LDSTEP(B, A, q1.x);
    LDSTEP(A, B, q1.y);
    LDSTEP(B, A, q1.z);
    LDSTEP(A, B, q1.w);
    hmm_step_r(a, w, A);
    b = 1;
    q0 = *(const int4*)(trow + 8);
    q1 = *(const int4*)(trow + 12);
  } else {
    int2 pp = *(const int2*)(trow + t0 - 2);   // 8B-aligned (t0 mult of 128)
    c12 = pp.x * 5 + pp.y; p2 = pp.y;
  }

  for (; b < CLEN / 8; b++) {
    int4 n0 = q0, n1 = q1;
    if (b + 1 < CLEN / 8) {               // distance-1 GLOBAL token prefetch
      n0 = *(const int4*)(trow + t0 + (b + 1) * 8);
      n1 = *(const int4*)(trow + t0 + (b + 1) * 8 + 4);
    }
    LDONLY(A, q0.x);
    LDSTEP(B, A, q0.y);
    LDSTEP(A, B, q0.z);
    LDSTEP(B, A, q0.w);
    LDSTEP(A, B, q1.x);
    LDSTEP(B, A, q1.y);
    LDSTEP(A, B, q1.z);
    LDSTEP(B, A, q1.w);
    hmm_step_r(a, w, B);
    if (b & 1) renorm(a, L);              // every 16 steps (prescale-safe)
    q0 = n0; q1 = n1;
  }

  // undo the x16 prescale exactly: chunk 0 ran 127 steps, others 128
  if (L > -1.0e38f) L -= (chunk == 0 ? 127.0f : 128.0f) * LOG16;

  // stash chunk matrix row in LDS (bf16 values, fp32 L)
  if (row < NLIVE) {
    const int base = (chunk * NLIVE + row) * 24;
    #pragma unroll
    for (int k = 0; k < 11; k++) {
      ushort2 p; p.x = f2bf(a[2 * k]); p.y = f2bf(a[2 * k + 1]);
      *(ushort2*)&sT[base + 2 * k] = p;
    }
    { ushort2 p; p.x = f2bf(a[22]); p.y = 0; *(ushort2*)&sT[base + 22] = p; }
    sL[chunk * NLIVE + row] = L;
  }
  __syncthreads();

  // ---- combine (wave 0 only): fold 16 chunk matrices, lane j = column j ----
  if (tid < 64) {
    const int lane = tid;
    const bool act = (lane < NLIVE);
    const int jc   = act ? lane : 0;

    const int tok0 = trow[0];
    const int idx0 = 96 + tok0;   // packed (4,4,tok0)

    float v = act ? sI[lane] * sBt[idx0 * 32 + lane] : 0.0f;
    float s = v;
    #pragma unroll
    for (int m = 1; m < 32; m <<= 1) s += __shfl_xor(s, m, 32);
    float ll = __logf(s) - LOG16;          // undo prescale on step 0
    v = act ? v * __fdividef(1.0f, s) : 0.0f;

    for (int c = 0; c < CHUNKS; c++) {
      float Lj  = act ? sL[c * NLIVE + lane] : -3.0e38f;
      float key = (act && v > 0.0f) ? Lj : -3.0e38f;
      float mx = key;
      #pragma unroll
      for (int m = 1; m < 32; m <<= 1) mx = fmaxf(mx, __shfl_xor(mx, m, 32));
      float wgt = (act && v > 0.0f) ? v * __expf(Lj - mx) : 0.0f;

      float nv = 0.0f;
      #pragma unroll
      for (int r = 0; r < NLIVE; r++) {
        float wr = __shfl(wgt, r, 64);
        nv += wr * __uint_as_float(((unsigned)sT[(c * NLIVE + r) * 24 + jc]) << 16);
      }
      float nva = act ? nv : 0.0f;
      float s2 = nva;
      #pragma unroll
      for (int m = 1; m < 32; m <<= 1) s2 += __shfl_xor(s2, m, 32);
      ll += mx + __logf(s2);
      v = act ? nv * __fdividef(1.0f, s2) : 0.0f;
    }

    if (lane == 0) out[seq] = ll;
  }
}

// ---------------------------------------------------------------------------
extern "C" void kernel_launch(void* const* d_in, const int* in_sizes, int n_in,
                              void* d_out, int out_size, void* d_ws, size_t ws_size,
                              hipStream_t stream) {
  const float* wT = (const float*)d_in[0];   // transition_kernel (10)
  const float* wE = (const float*)d_in[1];   // emission_kernel (5400)
  const float* wI = (const float*)d_in[2];   // init_kernel (25)
  const int* tokens = (const int*)d_in[3];   // (512, 2048) int32
  float* out = (float*)d_out;                // (512,) float32
  (void)d_ws; (void)ws_size;                 // workspace unused

  hmm_kernel<<<NSEQ, 512, 0, stream>>>(wT, wE, wI, tokens, out);
}

// Round 12
// 121.554 us; speedup vs baseline: 1.5292x; 1.1098x over previous
//
#include <hip/hip_runtime.h>
#include <hip/hip_bf16.h>
#include <math.h>

// ---------------------------------------------------------------------------
// CgpHmmCell forward: 512 seqs x 2048 steps x 25-state HMM (23 live states).
//
// ROUND-12 = R11 winner + PACKED-FP32 math via state-order permutation.
// The seven pass-through 3-chains (1-2-3, 4-5-6, 7-8-9, 10-11-12, 14-15-16,
// 17-18-19, 20-21-22) are interleaved pairwise:
//   pos: {1,4, 2,5, 3,6, 7,10, 8,11, 9,12, 14,17, 15,18, 16,19, 20,0, 21,13, 22,pad}
// so the shift a[j]<-a[j-1] maps register-pair k -> pair k+1 ALIGNED:
// 6 v_pk_mul_f32 handle 12 states' transition+emission. Head states use
// pk'd weight pairs ((n4,n14),(n7,n17),(n10,n20),(n0,n1) share inputs).
// Emission LDS rows and chunk matrices are stored in permuted order; the
// combine maps lane j -> position jp once. Arithmetic per op is identical.
//
// Lessons enforced: R4 never clamp VGPR below live set; R6 keep token
// prefetch; R7/8 LDS<->VALU trades lose; R11 renorm-16 + x16 prescale.
// ---------------------------------------------------------------------------

typedef float v2f __attribute__((ext_vector_type(2)));
typedef float v4f __attribute__((ext_vector_type(4)));

#define NSTATES 25
#define NLIVE   23
#define NFLAT   216
#define NPACK   100
#define TLEN    2048
#define NSEQ    512
#define CHUNKS  16
#define CLEN    128

#define LOG16 2.772588722239781f

// pos -> canonical state (pad slot = 23, dead)
__device__ __constant__ int PERMC[24] = {1,4,2,5,3,6,7,10,8,11,9,12,
                                         14,17,15,18,16,19,20,0,21,13,22,23};

// ---------------------------------------------------------------------------
// Compile-time emission map (validated: absmax 0.0 across rounds).
// ---------------------------------------------------------------------------
struct WMap { short m[NSTATES * NFLAT]; };

constexpr WMap make_wmap() {
  WMap w{};
  for (int i = 0; i < NSTATES * NFLAT; i++) w.m[i] = -2;
  const unsigned char ST[29] = {0,1,2,3,4,5,6,7,8,9,10,11,11,12,12,12,13,
                                14,15,16,17,18,19,20,21,22,23,23,24};
  const unsigned char M1[29] = {0x1F,0x1F,0x1F,0x11,0x18,0x14,0x1F,0x1F,0x1F,
                                0x1F,0x0F,0x0F,0x0F,0x08,0x08,0x08,0x0F,
                                0x1F,0x1F,0x1F,0x1F,0x1F,0x1F,0x1F,0x1F,0x1F,
                                0x0F,0x0F,0x20};
  const unsigned char M2[29] = {0x1F,0x1F,0x11,0x18,0x14,0x1F,0x1F,0x1F,0x1F,
                                0x1F,0x0F,0x08,0x08,0x01,0x01,0x04,0x0F,
                                0x1F,0x1F,0x1F,0x1F,0x1F,0x1F,0x1F,0x1F,0x1F,
                                0x0F,0x20,0x20};
  const unsigned char M3[29] = {0x0F,0x01,0x08,0x04,0x0F,0x0F,0x0F,0x0F,0x0F,
                                0x0F,0x08,0x01,0x04,0x01,0x04,0x01,0x0F,
                                0x0F,0x0F,0x0F,0x0F,0x0F,0x0F,0x0F,0x0F,0x0F,
                                0x20,0x20,0x20};
  const unsigned char TR[29] = {1,1,1,0,1,1,1,1,1,1,1,1,1,0,0,0,1,
                                1,1,1,1,1,1,1,1,1,1,1,0};
  int k = 0;
  for (int s = 0; s < 29; s++) {
    for (int c1 = 0; c1 < 6; c1++) {
      if (!((M1[s] >> c1) & 1)) continue;
      for (int c2 = 0; c2 < 6; c2++) {
        if (!((M2[s] >> c2) & 1)) continue;
        if (c1 != 4 && c2 == 4) continue;
        for (int c3 = 0; c3 < 6; c3++) {
          if (!((M3[s] >> c3) & 1)) continue;
          w.m[ST[s] * NFLAT + c1 * 36 + c2 * 6 + c3] =
              TR[s] ? (short)(k++) : (short)-1;
        }
      }
    }
  }
  return w;
}
__device__ __constant__ WMap WMAP = make_wmap();

// canonical state -> position (live states only)
__device__ __constant__ int POSA[NLIVE] = {19,0,2,4,1,3,5,6,8,10,7,9,11,21,
                                           12,14,16,13,15,17,18,20,22};

__device__ __forceinline__ unsigned short f2bf(float x) {  // RNE
  unsigned int u = __float_as_uint(x);
  u += 0x7fffu + ((u >> 16) & 1u);
  return (unsigned short)(u >> 16);
}

struct Wp {
  v2f w01, wA, wB, wC, wD, wE, wF;
  float w4, w5, w8, w11;
};

// ---------------------------------------------------------------------------
// One HMM step in permuted-pair layout, emission row in registers (F[0..5] =
// positions 0..23). 6 pk_mul shifts + pk'd head terms. Mapping verified
// against the canonical step (see header comment).
// ---------------------------------------------------------------------------
__device__ __forceinline__ void step_pk(v2f (&Q)[12], const v4f (&F)[6],
                                        const Wp& W) {
  float a0 = Q[9].y,  a3 = Q[2].x,  a6 = Q[2].y,  a9 = Q[5].x;
  float a12 = Q[5].y, a13 = Q[10].y, a16 = Q[8].x, a19 = Q[8].y, a22 = Q[11].x;
  float q9x = Q[9].x, q10x = Q[10].x;   // old a20, a21

  v2f t01 = a0 * W.w01;                  // (n0, n1)
  v2f t44 = a3 * W.wA + a16 * W.wB;      // (n4, n14)
  v2f t77 = a6 * W.wC + a19 * W.wD;      // (n7 partial, n17)
  float n7  = fmaf(a3, W.w4, t77.x);
  v2f tAA = a9 * W.wE + a22 * W.wF;      // (n10 partial, n20)
  float n10 = fmaf(a3, W.w5, fmaf(a6, W.w8, tAA.x));
  float n13 = fmaf(a13, W.w11, a12);

  // aligned shift pairs (transition weight 1.0) * emission pair
  v2f nQ1 = Q[0] * __builtin_shufflevector(F[0], F[0], 2, 3);  // (e2,e5)
  v2f nQ2 = Q[1] * __builtin_shufflevector(F[1], F[1], 0, 1);  // (e3,e6)
  v2f nQ4 = Q[3] * __builtin_shufflevector(F[2], F[2], 0, 1);  // (e8,e11)
  v2f nQ5 = Q[4] * __builtin_shufflevector(F[2], F[2], 2, 3);  // (e9,e12)
  v2f nQ7 = Q[6] * __builtin_shufflevector(F[3], F[3], 2, 3);  // (e15,e18)
  v2f nQ8 = Q[7] * __builtin_shufflevector(F[4], F[4], 0, 1);  // (e16,e19)

  Q[0]  = (v2f){ t01.y * F[0].x, t44.x * F[0].y };   // (n1*e1,  n4*e4)
  Q[3]  = (v2f){ n7    * F[1].z, n10   * F[1].w };   // (n7*e7,  n10*e10)
  Q[6]  = (v2f){ t44.y * F[3].x, t77.y * F[3].y };   // (n14*e14, n17*e17)
  Q[9]  = (v2f){ tAA.y * F[4].z, t01.x * F[4].w };   // (n20*e20, n0*e0)
  Q[10] = (v2f){ q9x   * F[5].x, n13   * F[5].y };   // (a20*e21, n13*e13)
  Q[11].x = q10x * F[5].z;                           // a21*e22 (pad .y stays)
  Q[1] = nQ1; Q[2] = nQ2; Q[4] = nQ4; Q[5] = nQ5; Q[7] = nQ7; Q[8] = nQ8;
}

__device__ __forceinline__ void renorm_pk(v2f (&Q)[12], float& L) {
  v2f acc = ((Q[0] + Q[1]) + (Q[2] + Q[3])) + ((Q[4] + Q[5]) + (Q[6] + Q[7]))
          + ((Q[8] + Q[9]) + (Q[10] + Q[11]));
  float s = acc.x + acc.y;
  if (s > 0.0f) {
    L += __logf(s);
    float r = __fdividef(1.0f, s);
    #pragma unroll
    for (int k = 0; k < 12; k++) Q[k] *= r;
  } else {
    L = -3.0e38f;  // row died; stays dead
  }
}

// load row for NEXT step, then compute the CURRENT one (R11 pipelining)
#define LDROW(F, nt_) { int nt = (nt_); \
  const v4f* er = (const v4f*)(sBt + (((c12 << 2) + nt) << 5)); \
  F[0] = er[0]; F[1] = er[1]; F[2] = er[2]; \
  F[3] = er[3]; F[4] = er[4]; F[5] = er[5]; \
  c12 = p2 * 5 + nt; p2 = nt; }
#define LDSTEP(Fn, Fc, nt_) { LDROW(Fn, nt_); step_pk(Q, Fc, W); }

// ---------------------------------------------------------------------------
// One kernel: block = sequence, 512 thr = 16 chunks x 32 lanes, CLEN=128.
// ---------------------------------------------------------------------------
__global__ __launch_bounds__(512, 4)
void hmm_kernel(const float* __restrict__ wT, const float* __restrict__ wE,
                const float* __restrict__ wI, const int* __restrict__ tokens,
                float* __restrict__ out) {
  __shared__ __align__(16) float          sBt[NPACK * 32];          // 12800 B
  __shared__ __align__(16) unsigned short sT[CHUNKS * NLIVE * 24];  // 17664 B
  __shared__ float sL[CHUNKS * NLIVE];                              //  1472 B
  __shared__ float sAW[24];
  __shared__ float sI[32];

  const int tid   = threadIdx.x;
  const int seq   = blockIdx.x;
  const int chunk = tid >> 5;
  const int row   = tid & 31;
  const int* trow = tokens + (size_t)seq * TLEN;

  // ---- per-block setup: emission rows (x16 prescale) in PERMUTED order ----
  for (int st = chunk; st < NLIVE; st += 16) {
    const int pos = POSA[st];
    float part = 0.0f;
    for (int c = row; c < NFLAT; c += 32) {
      short m = WMAP.m[st * NFLAT + c];
      if (m == -1) part += expf(1.0f);
      else if (m >= 0) part += expf(wE[m]);
    }
    #pragma unroll
    for (int m = 1; m < 32; m <<= 1) part += __shfl_xor(part, m, 32);
    float inv = 16.0f / part;
    for (int i = row; i < NPACK; i += 32) {
      int c12 = i >> 2, nt = i & 3;
      int p1 = c12 / 5, p2v = c12 - 5 * p1;
      int flat = p1 * 36 + p2v * 6 + nt;
      short m = WMAP.m[st * NFLAT + flat];
      float v = 0.0f;
      if (m == -1) v = expf(1.0f);
      else if (m >= 0) v = expf(wE[m]);
      sBt[i * 32 + pos] = v * inv;
    }
  }
  for (int i = tid; i < NPACK; i += 512) sBt[i * 32 + 23] = 0.0f;  // pad slot
  if (tid == 480) {
    // softmax of multi-entry A rows -> 21 packed weights (validated)
    const float w0 = wT[0], w1 = wT[1], w2 = wT[2], w3 = wT[3], w4 = wT[4];
    const float w5 = wT[5], w6 = wT[6], w7 = wT[7], w8 = wT[8], w9 = wT[9];
    { float e0 = expf(1.0f - w0), e1 = expf(w0), is = 1.0f / (e0 + e1);
      sAW[0] = e0 * is; sAW[1] = e1 * is; }
    { float e4 = expf(w1), e14 = expf(w3);
      float e7 = expf(1.0f - w9 * w9), e10 = expf(1.0f - w9 * w9 * w9);
      float is = 1.0f / (e4 + e14 + e7 + e10);
      sAW[2] = e4 * is;  sAW[3] = e14 * is;
      sAW[4] = e7 * is;  sAW[5] = e10 * is; }
    { float e7 = expf(w2), e17 = expf(w4), e10 = expf(1.0f - w9 * w9);
      float is = 1.0f / (e7 + e17 + e10);
      sAW[6] = e7 * is; sAW[7] = e17 * is; sAW[8] = e10 * is; }
    { float e20 = expf(w5), e10 = expf(1.0f - w5), is = 1.0f / (e20 + e10);
      sAW[9] = e20 * is; sAW[10] = e10 * is; }
    sAW[11] = 0.5f; sAW[12] = 0.5f;   // row 13
    { float e4 = expf(w6), e14 = expf(1.0f - w6), is = 1.0f / (e4 + e14);
      sAW[13] = e4 * is; sAW[14] = e14 * is; }
    { float e7 = expf(w7), e17 = expf(1.0f - w7), is = 1.0f / (e7 + e17);
      sAW[15] = e7 * is; sAW[16] = e17 * is; }
    { float e10 = expf(w8), e20 = expf(1.0f - w8), is = 1.0f / (e10 + e20);
      sAW[17] = e10 * is; sAW[18] = e20 * is; }
    sAW[19] = 0.5f; sAW[20] = 0.5f;
  } else if (tid == 481) {
    float e[9], s = 0.0f;
    for (int i = 0; i < 9; i++) { e[i] = expf(wI[i]); s += e[i]; }
    float inv = 1.0f / s;
    for (int i = 0; i < 9; i++) sI[i] = e[i] * inv;
    for (int i = 9; i < 32; i++) sI[i] = 0.0f;
  }
  __syncthreads();

  // A-weights: wave-uniform -> SGPRs, then packed pairs
  float w[21];
  #pragma unroll
  for (int i = 0; i < 21; i++)
    w[i] = __uint_as_float(
        (unsigned)__builtin_amdgcn_readfirstlane(__float_as_uint(sAW[i])));
  Wp W;
  W.w01 = (v2f){w[0],  w[1]};
  W.wA  = (v2f){w[2],  w[3]};
  W.wB  = (v2f){w[13], w[14]};
  W.wC  = (v2f){w[6],  w[7]};
  W.wD  = (v2f){w[15], w[16]};
  W.wE  = (v2f){w[10], w[9]};
  W.wF  = (v2f){w[17], w[18]};
  W.w4 = w[4]; W.w5 = w[5]; W.w8 = w[8]; W.w11 = w[11];

  // ---- scan ----
  const int t0 = chunk * CLEN;

  v2f Q[12];
  #pragma unroll
  for (int k = 0; k < 12; k++) {
    Q[k].x = (row == PERMC[2 * k]) ? 1.0f : 0.0f;
    Q[k].y = (row == PERMC[2 * k + 1]) ? 1.0f : 0.0f;
  }
  float L = 0.0f;

  v4f FA[6], FB[6];
  int c12, p2;
  int4 q0 = *(const int4*)(trow + t0);
  int4 q1 = *(const int4*)(trow + t0 + 4);

  int b = 0;
  if (chunk == 0) {
    // body 0 = steps t = 1..7 (t = 0 folded into the combine's init)
    c12 = 20 + q0.x; p2 = q0.x;
    LDROW(FA, q0.y);
    LDSTEP(FB, FA, q0.z);
    LDSTEP(FA, FB, q0.w);
    LDSTEP(FB, FA, q1.x);
    LDSTEP(FA, FB, q1.y);
    LDSTEP(FB, FA, q1.z);
    LDSTEP(FA, FB, q1.w);
    step_pk(Q, FA, W);
    b = 1;
    q0 = *(const int4*)(trow + 8);
    q1 = *(const int4*)(trow + 12);
  } else {
    int2 pp = *(const int2*)(trow + t0 - 2);
    c12 = pp.x * 5 + pp.y; p2 = pp.y;
  }

  for (; b < CLEN / 8; b++) {
    int4 n0 = q0, n1 = q1;
    if (b + 1 < CLEN / 8) {               // distance-1 global token prefetch
      n0 = *(const int4*)(trow + t0 + (b + 1) * 8);
      n1 = *(const int4*)(trow + t0 + (b + 1) * 8 + 4);
    }
    LDROW(FA, q0.x);
    LDSTEP(FB, FA, q0.y);
    LDSTEP(FA, FB, q0.z);
    LDSTEP(FB, FA, q0.w);
    LDSTEP(FA, FB, q1.x);
    LDSTEP(FB, FA, q1.y);
    LDSTEP(FA, FB, q1.z);
    LDSTEP(FB, FA, q1.w);
    step_pk(Q, FB, W);
    if (b & 1) renorm_pk(Q, L);           // every 16 steps (x16 prescale)
    q0 = n0; q1 = n1;
  }

  // undo the x16 prescale exactly: chunk 0 ran 127 steps, others 128
  if (L > -1.0e38f) L -= (chunk == 0 ? 127.0f : 128.0f) * LOG16;

  // stash chunk matrix row (bf16, PERMUTED position order) + fp32 L
  if (row < NLIVE) {
    const int base = (chunk * NLIVE + row) * 24;
    #pragma unroll
    for (int k = 0; k < 12; k++) {
      ushort2 p; p.x = f2bf(Q[k].x); p.y = f2bf(Q[k].y);
      *(ushort2*)&sT[base + 2 * k] = p;
    }
    sL[chunk * NLIVE + row] = L;
  }
  __syncthreads();

  // ---- combine (wave 0): fold 16 chunk matrices; lane j = canonical col ----
  if (tid < 64) {
    const int lane = tid;
    const bool act = (lane < NLIVE);

    int jp = 23;                          // lane's PERMUTED position
    #pragma unroll
    for (int pos = 0; pos < 23; pos++)
      if (PERMC[pos] == lane) jp = pos;

    const int tok0 = trow[0];
    const int idx0 = 96 + tok0;           // packed (4,4,tok0)

    float v = act ? sI[lane] * sBt[idx0 * 32 + jp] : 0.0f;
    float s = v;
    #pragma unroll
    for (int m = 1; m < 32; m <<= 1) s += __shfl_xor(s, m, 32);
    float ll = __logf(s) - LOG16;         // undo prescale on step 0
    v = act ? v * __fdividef(1.0f, s) : 0.0f;

    for (int c = 0; c < CHUNKS; c++) {
      float Lj  = act ? sL[c * NLIVE + lane] : -3.0e38f;
      float key = (act && v > 0.0f) ? Lj : -3.0e38f;
      float mx = key;
      #pragma unroll
      for (int m = 1; m < 32; m <<= 1) mx = fmaxf(mx, __shfl_xor(mx, m, 32));
      float wgt = (act && v > 0.0f) ? v * __expf(Lj - mx) : 0.0f;

      float nv = 0.0f;
      #pragma unroll
      for (int r = 0; r < NLIVE; r++) {
        float wr = __shfl(wgt, r, 64);
        nv += wr * __uint_as_float(((unsigned)sT[(c * NLIVE + r) * 24 + jp]) << 16);
      }
      float nva = act ? nv : 0.0f;
      float s2 = nva;
      #pragma unroll
      for (int m = 1; m < 32; m <<= 1) s2 += __shfl_xor(s2, m, 32);
      ll += mx + __logf(s2);
      v = act ? nv * __fdividef(1.0f, s2) : 0.0f;
    }

    if (lane == 0) out[seq] = ll;
  }
}

// ---------------------------------------------------------------------------
extern "C" void kernel_launch(void* const* d_in, const int* in_sizes, int n_in,
                              void* d_out, int out_size, void* d_ws, size_t ws_size,
                              hipStream_t stream) {
  const float* wT = (const float*)d_in[0];   // transition_kernel (10)
  const float* wE = (const float*)d_in[1];   // emission_kernel (5400)
  const float* wI = (const float*)d_in[2];   // init_kernel (25)
  const int* tokens = (const int*)d_in[3];   // (512, 2048) int32
  float* out = (float*)d_out;                // (512,) float32
  (void)d_ws; (void)ws_size;                 // workspace unused

  hmm_kernel<<<NSEQ, 512, 0, stream>>>(wT, wE, wI, tokens, out);
}